// Round 13
// baseline (104.706 us; speedup 1.0000x reference)
//
#include <hip/hip_runtime.h>

#define NV 8
#define NB 16
#define LMAX 4096
#define ND 1024
#define CHUNK 128
#define NCHUNK (LMAX / CHUNK)   // 32 chunks -> 512 blocks
#define EPS_ 1e-6f
// exp(-10*s) == exp2(s * (-10*log2(e)))
#define NEXP10 (-14.426950408889634f)

// ws layout: pnum[NB][NCHUNK][NV][ND] f32 (16 MB), pden[NB][NCHUNK][NV] f32,
//            counters[NB] int
#define PNUM_FLOATS ((size_t)NB * NCHUNK * NV * ND)
#define PDEN_FLOATS ((size_t)NB * NCHUNK * NV)

__global__ __launch_bounds__(256, 4) void dvs_fused(
    const float* __restrict__ v_pad,
    const float* __restrict__ centers,
    const int* __restrict__ grid_thws,
    float* __restrict__ pnum,
    float* __restrict__ pden,
    int* __restrict__ counters,
    float* __restrict__ out)
{
    const int bid   = blockIdx.x;
    const int b     = bid >> 5;             // / NCHUNK
    const int chunk = bid & (NCHUNK - 1);
    const int H  = grid_thws[b * 3 + 1];
    const int W  = grid_thws[b * 3 + 2];
    const int HW = H * W;
    const int nc = (HW + CHUNK - 1) / CHUNK;   // active chunks, nc >= 8 (HW >= 1024)
    const int l0 = chunk * CHUNK;
    if (l0 >= HW) return;                   // fully-masked chunk: no reads, no writes
    // valid rows in this chunk, rounded up to pipeline granularity (4)
    const int rr = (min(CHUNK, HW - l0) + 3) & ~3;

    __shared__ __align__(16) float wlds[CHUNK][NV];   // 4 KB: weights w[row][view]
    __shared__ int ticket;
    __shared__ float dls[NV];

    const int t = threadIdx.x;

    // ---- issue the first 4 row-loads BEFORE the weight phase (independent)
    const float4* __restrict__ src =
        (const float4*)v_pad + ((size_t)b * LMAX + l0) * (ND / 4) + t;
    float4 c0 = src[0 * 256];
    float4 c1 = src[1 * 256];
    float4 c2 = src[2 * 256];
    float4 c3 = src[3 * 256];

    // ---- weight phase: 1024 weights, 4 per thread, once per block
    const float invH = 1.0f / (float)H;
    const float invW = 1.0f / (float)W;
#pragma unroll
    for (int g = 0; g < 4; ++g) {
        const int idx = t + g * 256;
        const int row = idx >> 3;           // 0..127
        const int v   = idx & 7;
        const int l   = l0 + row;
        const int i   = l / W;
        const int j   = l - i * W;
        const float y = ((float)i + 0.5f) * invH;
        const float x = ((float)j + 0.5f) * invW;
        const float2 c = ((const float2*)centers)[b * NV + v];
        const float dx = c.x - x;
        const float dy = c.y - y;
        const float s  = fmaf(dy, dy, dx * dx);
        wlds[row][v] = (l < HW) ? exp2f(s * NEXP10) : 0.0f;
    }
    __syncthreads();

    // ---- pden: wave 0, lane (rg = t>>3, v = t&7), butterfly over rg bits
    const size_t pbase = (size_t)(b * NCHUNK + chunk) * NV;
    if (t < 64) {
        const int rg = t >> 3;
        const int v  = t & 7;
        float s = 0.0f;
#pragma unroll
        for (int k = 0; k < CHUNK / 8; ++k) s += wlds[rg + 8 * k][v];
        s += __shfl_xor(s, 8);
        s += __shfl_xor(s, 16);
        s += __shfl_xor(s, 32);
        if (rg == 0) pden[pbase + v] = s;
    }

    float acc[NV][4];
#pragma unroll
    for (int v = 0; v < NV; ++v)
#pragma unroll
        for (int k = 0; k < 4; ++k) acc[v][k] = 0.0f;

    auto proc = [&](const int r, const float4 r4) {
        float w[NV];
        *(float4*)&w[0] = *(const float4*)&wlds[r][0];
        *(float4*)&w[4] = *(const float4*)&wlds[r][4];
#pragma unroll
        for (int v = 0; v < NV; ++v) {
            acc[v][0] = fmaf(w[v], r4.x, acc[v][0]);
            acc[v][1] = fmaf(w[v], r4.y, acc[v][1]);
            acc[v][2] = fmaf(w[v], r4.z, acc[v][2]);
            acc[v][3] = fmaf(w[v], r4.w, acc[v][3]);
        }
    };

    // 4-deep software pipeline over the valid rows (dynamic bound rr)
    for (int r = 0; r < rr; r += 4) {
        float4 n0 = c0, n1 = c1, n2 = c2, n3 = c3;
        if (r + 4 < rr) {                   // uniform branch
            n0 = src[(r + 4) * 256];
            n1 = src[(r + 5) * 256];
            n2 = src[(r + 6) * 256];
            n3 = src[(r + 7) * 256];
        }
        proc(r + 0, c0); proc(r + 1, c1); proc(r + 2, c2); proc(r + 3, c3);
        c0 = n0; c1 = n1; c2 = n2; c3 = n3;
    }

    // private partial store — no atomics on data
    float4* np_ = (float4*)pnum;
#pragma unroll
    for (int v = 0; v < NV; ++v)
        np_[(pbase + v) * (ND / 4) + t] =
            make_float4(acc[v][0], acc[v][1], acc[v][2], acc[v][3]);

    // ---- fused reduction: last 8 arrivals reduce, AFTER waiting for all ----
    __threadfence();                        // release: partials visible device-wide
    if (t == 0)
        ticket = atomicAdd(&counters[b], 1);
    __syncthreads();
    const int tk = ticket;
    if (tk < nc - 8) return;                // not among the last 8 arrivals
    // wait until ALL nc blocks of this batch have released their partials
    if (t == 0) {
        while (__hip_atomic_load(&counters[b], __ATOMIC_ACQUIRE,
                                 __HIP_MEMORY_SCOPE_AGENT) < nc) { }
    }
    __syncthreads();
    __threadfence();                        // acquire: see all partials
    const int ridx = tk - (nc - 8);         // 0..7: which column-slice to reduce

    if (t < NV) {
        float s = 0.0f;
        for (int c = 0; c < nc; ++c)
            s += pden[(size_t)(b * NCHUNK + c) * NV + t];
        dls[t] = s;
    }
    __syncthreads();

    // thread t: view v = t>>5, float4-column col = ridx*32 + (t&31)
    const int v   = t >> 5;
    const int col = ridx * 32 + (t & 31);
    const float4* rp = (const float4*)pnum;
    const size_t cstride = (size_t)NV * (ND / 4);        // float4s between chunks
    const size_t base = (size_t)b * NCHUNK * cstride + (size_t)v * (ND / 4) + col;

    float4 s0 = make_float4(0.f, 0.f, 0.f, 0.f), s1 = s0, s2 = s0, s3 = s0;
    int c = 0;
    for (; c + 4 <= nc; c += 4) {           // 4 loads in flight
        float4 p0 = rp[base + (size_t)(c + 0) * cstride];
        float4 p1 = rp[base + (size_t)(c + 1) * cstride];
        float4 p2 = rp[base + (size_t)(c + 2) * cstride];
        float4 p3 = rp[base + (size_t)(c + 3) * cstride];
        s0.x += p0.x; s0.y += p0.y; s0.z += p0.z; s0.w += p0.w;
        s1.x += p1.x; s1.y += p1.y; s1.z += p1.z; s1.w += p1.w;
        s2.x += p2.x; s2.y += p2.y; s2.z += p2.z; s2.w += p2.w;
        s3.x += p3.x; s3.y += p3.y; s3.z += p3.z; s3.w += p3.w;
    }
    for (; c < nc; ++c) {
        float4 p0 = rp[base + (size_t)c * cstride];
        s0.x += p0.x; s0.y += p0.y; s0.z += p0.z; s0.w += p0.w;
    }
    const float inv = 1.0f / (dls[v] + EPS_);
    float4 o = make_float4((s0.x + s1.x + s2.x + s3.x) * inv,
                           (s0.y + s1.y + s2.y + s3.y) * inv,
                           (s0.z + s1.z + s2.z + s3.z) * inv,
                           (s0.w + s1.w + s2.w + s3.w) * inv);
    ((float4*)out)[(size_t)(b * NV + v) * (ND / 4) + col] = o;
}

extern "C" void kernel_launch(void* const* d_in, const int* in_sizes, int n_in,
                              void* d_out, int out_size, void* d_ws, size_t ws_size,
                              hipStream_t stream) {
    const float* v_pad     = (const float*)d_in[0];
    const float* centers   = (const float*)d_in[1];
    // d_in[2] = v_len (== H*W), unused
    const int*   grid_thws = (const int*)d_in[3];

    float* pnum     = (float*)d_ws;
    float* pden     = pnum + PNUM_FLOATS;
    int*   counters = (int*)(pden + PDEN_FLOATS);

    hipMemsetAsync(counters, 0, NB * sizeof(int), stream);
    dvs_fused<<<NB * NCHUNK, 256, 0, stream>>>(v_pad, centers, grid_thws,
                                               pnum, pden, counters, (float*)d_out);
}

// Round 14
// 33.304 us; speedup vs baseline: 3.1439x; 3.1439x over previous
//
#include <hip/hip_runtime.h>

#define NV 8
#define NB 16
#define LMAX 4096
#define ND 1024
#define CHUNK 128
#define NCHUNK (LMAX / CHUNK)   // 32 chunks -> 512 blocks
#define EPS_ 1e-6f
// exp(-10*s) == exp2(s * (-10*log2(e)))
#define NEXP10 (-14.426950408889634f)

// ws layout: pnum[NB][NCHUNK][NV][ND] floats (16 MB), then pden[NB][NCHUNK][NV]
#define PNUM_FLOATS ((size_t)NB * NCHUNK * NV * ND)

__global__ __launch_bounds__(256, 4) void dvs_accum(
    const float* __restrict__ v_pad,
    const float* __restrict__ centers,
    const int* __restrict__ grid_thws,
    float* __restrict__ pnum,
    float* __restrict__ pden)
{
    const int bid   = blockIdx.x;
    const int b     = bid >> 5;             // / NCHUNK
    const int chunk = bid & (NCHUNK - 1);
    const int H  = grid_thws[b * 3 + 1];
    const int W  = grid_thws[b * 3 + 2];
    const int HW = H * W;
    const int l0 = chunk * CHUNK;
    if (l0 >= HW) return;                   // fully-masked chunk: no reads, no writes
    // valid rows in this chunk, rounded up to pipeline granularity (4)
    const int rr = (min(CHUNK, HW - l0) + 3) & ~3;

    __shared__ __align__(16) float wlds[CHUNK][NV];   // 4 KB: weights w[row][view]

    const int t = threadIdx.x;

    // ---- issue the first 4 row-loads BEFORE the weight phase (independent)
    const float4* __restrict__ src =
        (const float4*)v_pad + ((size_t)b * LMAX + l0) * (ND / 4) + t;
    float4 c0 = src[0 * 256];
    float4 c1 = src[1 * 256];
    float4 c2 = src[2 * 256];
    float4 c3 = src[3 * 256];

    // ---- weight phase: 1024 weights, 4 per thread, once per block
    const float invH = 1.0f / (float)H;
    const float invW = 1.0f / (float)W;
#pragma unroll
    for (int g = 0; g < 4; ++g) {
        const int idx = t + g * 256;
        const int row = idx >> 3;           // 0..127
        const int v   = idx & 7;
        const int l   = l0 + row;
        const int i   = l / W;
        const int j   = l - i * W;
        const float y = ((float)i + 0.5f) * invH;
        const float x = ((float)j + 0.5f) * invW;
        const float2 c = ((const float2*)centers)[b * NV + v];
        const float dx = c.x - x;
        const float dy = c.y - y;
        const float s  = fmaf(dy, dy, dx * dx);
        wlds[row][v] = (l < HW) ? exp2f(s * NEXP10) : 0.0f;
    }
    __syncthreads();

    // ---- pden: wave 0, lane handles (rg = t>>3, v = t&7): 16 rows each,
    //      then butterfly over rg bits (masks 8,16,32)
    const size_t pbase = (size_t)(b * NCHUNK + chunk) * NV;
    if (t < 64) {
        const int rg = t >> 3;
        const int v  = t & 7;
        float s = 0.0f;
#pragma unroll
        for (int k = 0; k < CHUNK / 8; ++k) s += wlds[rg + 8 * k][v];
        s += __shfl_xor(s, 8);
        s += __shfl_xor(s, 16);
        s += __shfl_xor(s, 32);
        if (rg == 0) pden[pbase + v] = s;
    }

    float acc[NV][4];
#pragma unroll
    for (int v = 0; v < NV; ++v)
#pragma unroll
        for (int k = 0; k < 4; ++k) acc[v][k] = 0.0f;

    auto proc = [&](const int r, const float4 r4) {
        float w[NV];
        *(float4*)&w[0] = *(const float4*)&wlds[r][0];
        *(float4*)&w[4] = *(const float4*)&wlds[r][4];
#pragma unroll
        for (int v = 0; v < NV; ++v) {
            acc[v][0] = fmaf(w[v], r4.x, acc[v][0]);
            acc[v][1] = fmaf(w[v], r4.y, acc[v][1]);
            acc[v][2] = fmaf(w[v], r4.z, acc[v][2]);
            acc[v][3] = fmaf(w[v], r4.w, acc[v][3]);
        }
    };

    // 4-deep software pipeline over the valid rows (dynamic bound rr)
    for (int r = 0; r < rr; r += 4) {
        float4 n0 = c0, n1 = c1, n2 = c2, n3 = c3;
        if (r + 4 < rr) {                   // uniform branch
            n0 = src[(r + 4) * 256];
            n1 = src[(r + 5) * 256];
            n2 = src[(r + 6) * 256];
            n3 = src[(r + 7) * 256];
        }
        proc(r + 0, c0); proc(r + 1, c1); proc(r + 2, c2); proc(r + 3, c3);
        c0 = n0; c1 = n1; c2 = n2; c3 = n3;
    }

    // private partial store — no atomics
    float4* np_ = (float4*)pnum;
#pragma unroll
    for (int v = 0; v < NV; ++v)
        np_[(pbase + v) * (ND / 4) + t] =
            make_float4(acc[v][0], acc[v][1], acc[v][2], acc[v][3]);
}

// 512 one-wave blocks: (b, v, quarter-of-d). Each lane owns one float4.
__global__ __launch_bounds__(64) void dvs_reduce(
    const float* __restrict__ pnum,
    const float* __restrict__ pden,
    const int* __restrict__ grid_thws,
    float* __restrict__ out)
{
    const int bv = blockIdx.x >> 2;         // 0..127  (b*NV + v)
    const int q  = blockIdx.x & 3;          // quarter of d
    const int b  = bv >> 3;
    const int v  = bv & (NV - 1);
    const int HW = grid_thws[b * 3 + 1] * grid_thws[b * 3 + 2];
    const int nc = (HW + CHUNK - 1) / CHUNK;
    const int t  = threadIdx.x;             // 0..63
    const int f4 = q * 64 + t;              // float4 index within row, 0..255

    const float4* np_ = (const float4*)pnum;
    const size_t cstride = (size_t)NV * (ND / 4);
    const size_t base = ((size_t)b * NCHUNK * NV + v) * (ND / 4) + f4;
    const int dbase = b * NCHUNK * NV + v;

    float4 s0 = make_float4(0.f, 0.f, 0.f, 0.f), s1 = s0, s2 = s0, s3 = s0;
    float d0 = 0.f, d1 = 0.f, d2 = 0.f, d3 = 0.f;
    int c = 0;
    for (; c + 4 <= nc; c += 4) {           // 4 loads in flight
        float4 p0 = np_[base + (size_t)(c + 0) * cstride];
        float4 p1 = np_[base + (size_t)(c + 1) * cstride];
        float4 p2 = np_[base + (size_t)(c + 2) * cstride];
        float4 p3 = np_[base + (size_t)(c + 3) * cstride];
        d0 += pden[dbase + (c + 0) * NV];
        d1 += pden[dbase + (c + 1) * NV];
        d2 += pden[dbase + (c + 2) * NV];
        d3 += pden[dbase + (c + 3) * NV];
        s0.x += p0.x; s0.y += p0.y; s0.z += p0.z; s0.w += p0.w;
        s1.x += p1.x; s1.y += p1.y; s1.z += p1.z; s1.w += p1.w;
        s2.x += p2.x; s2.y += p2.y; s2.z += p2.z; s2.w += p2.w;
        s3.x += p3.x; s3.y += p3.y; s3.z += p3.z; s3.w += p3.w;
    }
    for (; c < nc; ++c) {
        float4 p0 = np_[base + (size_t)c * cstride];
        d0 += pden[dbase + c * NV];
        s0.x += p0.x; s0.y += p0.y; s0.z += p0.z; s0.w += p0.w;
    }
    const float inv = 1.0f / (d0 + d1 + d2 + d3 + EPS_);
    float4 o = make_float4((s0.x + s1.x + s2.x + s3.x) * inv,
                           (s0.y + s1.y + s2.y + s3.y) * inv,
                           (s0.z + s1.z + s2.z + s3.z) * inv,
                           (s0.w + s1.w + s2.w + s3.w) * inv);
    ((float4*)out)[(size_t)bv * (ND / 4) + f4] = o;
}

extern "C" void kernel_launch(void* const* d_in, const int* in_sizes, int n_in,
                              void* d_out, int out_size, void* d_ws, size_t ws_size,
                              hipStream_t stream) {
    const float* v_pad     = (const float*)d_in[0];
    const float* centers   = (const float*)d_in[1];
    // d_in[2] = v_len (== H*W), unused
    const int*   grid_thws = (const int*)d_in[3];

    float* pnum = (float*)d_ws;
    float* pden = pnum + PNUM_FLOATS;

    dvs_accum<<<NB * NCHUNK, 256, 0, stream>>>(v_pad, centers, grid_thws, pnum, pden);
    dvs_reduce<<<NB * NV * 4, 64, 0, stream>>>(pnum, pden, grid_thws, (float*)d_out);
}